// Round 4
// baseline (755.297 us; speedup 1.0000x reference)
//
#include <hip/hip_runtime.h>

typedef _Float16 half8 __attribute__((ext_vector_type(8)));
typedef float floatx4 __attribute__((ext_vector_type(4)));

// global -> LDS async copy, 16B per lane. LDS dest is wave-uniform base;
// HW scatters lane i to base + i*16 (m104/m108).
__device__ __forceinline__ void g2lds16(const void* g, void* l) {
    __builtin_amdgcn_global_load_lds(
        (const __attribute__((address_space(1))) void*)(unsigned long long)g,
        (__attribute__((address_space(3))) void*)(unsigned int)(unsigned long long)l,
        16, 0, 0);
}

// ---------------- CSR build ----------------

__global__ __launch_bounds__(256) void hist_kernel(const int* __restrict__ dst,
                                                   int* __restrict__ count, int E) {
    int e = blockIdx.x * 256 + threadIdx.x;
    if (e < E) atomicAdd(&count[dst[e]], 1);
}

__global__ __launch_bounds__(1024) void scan_a(const int* __restrict__ count,
                                               int* __restrict__ incl,
                                               int* __restrict__ bsum, int N) {
    __shared__ int s[1024];
    int tid = threadIdx.x;
    int i = blockIdx.x * 1024 + tid;
    int v = (i < N) ? count[i] : 0;
    s[tid] = v;
    __syncthreads();
    for (int off = 1; off < 1024; off <<= 1) {
        int t = (tid >= off) ? s[tid - off] : 0;
        __syncthreads();
        s[tid] += t;
        __syncthreads();
    }
    if (i < N) incl[i] = s[tid];
    if (tid == 1023) bsum[blockIdx.x] = s[1023];
}

// parallel exclusive scan over NB block sums (NB <= 1024)
__global__ __launch_bounds__(1024) void scan_b(const int* __restrict__ bsum,
                                               int* __restrict__ boff, int NB) {
    __shared__ int s[1024];
    int tid = threadIdx.x;
    int v = (tid < NB) ? bsum[tid] : 0;
    s[tid] = v;
    __syncthreads();
    for (int off = 1; off < 1024; off <<= 1) {
        int t = (tid >= off) ? s[tid - off] : 0;
        __syncthreads();
        s[tid] += t;
        __syncthreads();
    }
    if (tid < NB) boff[tid] = s[tid] - v;   // exclusive
}

__global__ __launch_bounds__(1024) void scan_c(const int* __restrict__ count,
                                               const int* __restrict__ incl,
                                               const int* __restrict__ boff,
                                               int* __restrict__ rowptr,
                                               int* __restrict__ cursor, int N) {
    int i = blockIdx.x * 1024 + threadIdx.x;
    if (i < N) {
        int excl = incl[i] - count[i] + boff[blockIdx.x];
        rowptr[i] = excl;
        cursor[i] = excl;
        if (i == N - 1) rowptr[N] = incl[i] + boff[blockIdx.x];
    }
}

// packed scatter: one 8B store per edge (src, val-bits)
__global__ __launch_bounds__(256) void scatter_kernel(const int* __restrict__ src,
                                                      const int* __restrict__ dst,
                                                      const float* __restrict__ val,
                                                      int* __restrict__ cursor,
                                                      int2* __restrict__ ssv, int E) {
    int e = blockIdx.x * 256 + threadIdx.x;
    if (e < E) {
        int d = dst[e];
        int pos = atomicAdd(&cursor[d], 1);
        int2 p;
        p.x = src[e];
        p.y = __float_as_int(val[e]);
        ssv[pos] = p;
    }
}

// ---------------- weight prep: fp32 -> fp16 hi/lo, transposed [n][k] ----------------

__global__ __launch_bounds__(256) void prep_w1(const float* __restrict__ W1,
                                               _Float16* __restrict__ Whi,
                                               _Float16* __restrict__ Wlo) {
    int tid = blockIdx.x * 256 + threadIdx.x;   // 65536
    int n = tid >> 9;        // 0..127
    int k = tid & 511;       // 0..511
    float w = W1[(size_t)k * 128 + n];
    _Float16 h = (_Float16)w;
    Whi[tid] = h;
    Wlo[tid] = (_Float16)(w - (float)h);
}

__global__ __launch_bounds__(256) void prep_w2(const float* __restrict__ W2,
                                               _Float16* __restrict__ Whi,
                                               _Float16* __restrict__ Wlo) {
    int tid = blockIdx.x * 256 + threadIdx.x;   // 8192
    int n = tid >> 7;        // 0..63
    int k = tid & 127;       // 0..127
    float w = W2[(size_t)k * 64 + n];
    _Float16 h = (_Float16)w;
    Whi[tid] = h;
    Wlo[tid] = (_Float16)(w - (float)h);
}

__device__ __forceinline__ void split8(float4 f0, float4 f1, half8& h, half8& l) {
    float f[8] = {f0.x, f0.y, f0.z, f0.w, f1.x, f1.y, f1.z, f1.w};
#pragma unroll
    for (int j = 0; j < 8; ++j) {
        _Float16 hi = (_Float16)f[j];
        h[j] = hi;
        l[j] = (_Float16)(f[j] - (float)hi);
    }
}

// ---------------- GEMM1: [M,512]@[512,128]+b1, split-fp16 MFMA ----------------
// BM=128; wave w owns rows m0=bm+w*32 (2 m-tiles), full N=128 (8 n-tiles).
// B (hi+lo) double-buffered in LDS via global_load_lds; A double-buffered in
// registers (prefetch i+1 right after barrier i so the barrier's vmcnt(0)
// drain lands a full compute-iteration after issue).

__global__ __launch_bounds__(256) void gemm1_mfma(const float* __restrict__ X,
                                                  const _Float16* __restrict__ Whi,
                                                  const _Float16* __restrict__ Wlo,
                                                  const float* __restrict__ bias,
                                                  float* __restrict__ out, int M) {
    __shared__ char smem[2 * 16384];
    int t = threadIdx.x;
    int w = t >> 6;
    int lane = t & 63;
    int quad = lane >> 4;
    int l16 = lane & 15;
    int bm = blockIdx.x * 128;
    int m0 = bm + w * 32;

    int ra0 = min(m0 + l16, M - 1);
    int ra1 = min(m0 + 16 + l16, M - 1);
    const float* a0p = X + (size_t)ra0 * 512 + quad * 8;
    const float* a1p = X + (size_t)ra1 * 512 + quad * 8;

    // staging: wave w owns chunks w*4..w*4+3 (1 KB each) of the 16 KB buffer
    int chunk0 = w * 4;
    const _Float16* gsrc[4];
#pragma unroll
    for (int c = 0; c < 4; ++c) {
        int idx = (chunk0 + c) * 1024 + lane * 16;  // byte index in buffer
        int sec = idx >> 13;                        // 0 = hi, 1 = lo
        int row = (idx & 8191) >> 6;                // n row
        int kch = (idx >> 4) & 3;                   // 16B chunk along k
        gsrc[c] = (sec ? Wlo : Whi) + (size_t)row * 512 + kch * 8;
    }
    // prologue: stage k0=0 into buf 0; prefetch A(0) into regs
#pragma unroll
    for (int c = 0; c < 4; ++c)
        g2lds16(gsrc[c], smem + (chunk0 + c) * 1024);
    float4 af00 = *(const float4*)(a0p);
    float4 af01 = *(const float4*)(a0p + 4);
    float4 af10 = *(const float4*)(a1p);
    float4 af11 = *(const float4*)(a1p + 4);

    floatx4 acc[2][8];
#pragma unroll
    for (int mt = 0; mt < 2; ++mt)
#pragma unroll
        for (int nt = 0; nt < 8; ++nt) acc[mt][nt] = (floatx4){0.f, 0.f, 0.f, 0.f};

    for (int i = 0; i < 16; ++i) {
        int k0 = i * 32;
        __syncthreads();  // buf(i) staged, A(i) regs landed
        if (i < 15) {
            char* nbuf = smem + ((i + 1) & 1) * 16384;
#pragma unroll
            for (int c = 0; c < 4; ++c)
                g2lds16(gsrc[c] + k0 + 32, nbuf + (chunk0 + c) * 1024);
        }
        // prefetch A(i+1) into next regs (in flight through this iter's MFMAs)
        float4 nf00 = af00, nf01 = af01, nf10 = af10, nf11 = af11;
        if (i < 15) {
            nf00 = *(const float4*)(a0p + k0 + 32);
            nf01 = *(const float4*)(a0p + k0 + 36);
            nf10 = *(const float4*)(a1p + k0 + 32);
            nf11 = *(const float4*)(a1p + k0 + 36);
        }
        const char* buf = smem + (i & 1) * 16384;
        half8 bh[8], bl[8];
#pragma unroll
        for (int nt = 0; nt < 8; ++nt) {
            int off = (nt * 16 + l16) * 64 + quad * 16;
            bh[nt] = *(const half8*)(buf + off);
            bl[nt] = *(const half8*)(buf + 8192 + off);
        }
        half8 ah0, al0, ah1, al1;
        split8(af00, af01, ah0, al0);
        split8(af10, af11, ah1, al1);
#pragma unroll
        for (int nt = 0; nt < 8; ++nt) {
            acc[0][nt] = __builtin_amdgcn_mfma_f32_16x16x32_f16(ah0, bh[nt], acc[0][nt], 0, 0, 0);
            acc[1][nt] = __builtin_amdgcn_mfma_f32_16x16x32_f16(ah1, bh[nt], acc[1][nt], 0, 0, 0);
            acc[0][nt] = __builtin_amdgcn_mfma_f32_16x16x32_f16(ah0, bl[nt], acc[0][nt], 0, 0, 0);
            acc[1][nt] = __builtin_amdgcn_mfma_f32_16x16x32_f16(ah1, bl[nt], acc[1][nt], 0, 0, 0);
            acc[0][nt] = __builtin_amdgcn_mfma_f32_16x16x32_f16(al0, bh[nt], acc[0][nt], 0, 0, 0);
            acc[1][nt] = __builtin_amdgcn_mfma_f32_16x16x32_f16(al1, bh[nt], acc[1][nt], 0, 0, 0);
        }
        af00 = nf00; af01 = nf01; af10 = nf10; af11 = nf11;
    }

    // D[row = quad*4+r][col = l16] per 16x16 tile (m89-verified)
#pragma unroll
    for (int nt = 0; nt < 8; ++nt) {
        int col = nt * 16 + l16;
        float bv = bias[col];
#pragma unroll
        for (int mt = 0; mt < 2; ++mt)
#pragma unroll
            for (int r = 0; r < 4; ++r) {
                int row = m0 + mt * 16 + quad * 4 + r;
                if (row < M) out[(size_t)row * 128 + col] = acc[mt][nt][r] + bv;
            }
    }
}

// ---------------- GEMM2: relu([M,128])@[128,64]+b2, split-fp16 MFMA ----------------

__global__ __launch_bounds__(256) void gemm2_mfma(const float* __restrict__ H,
                                                  const _Float16* __restrict__ Whi,
                                                  const _Float16* __restrict__ Wlo,
                                                  const float* __restrict__ bias,
                                                  float* __restrict__ out, int M) {
    __shared__ char smem[2 * 64 * 320];  // 40960 B
    int t = threadIdx.x;
#pragma unroll
    for (int i = 0; i < 4; ++i) {
        int gidx = i * 256 + t;          // 0..1023 float4s
        int row = gidx >> 4, col = gidx & 15;
        *(float4*)(smem + row * 320 + col * 16) = ((const float4*)Whi)[gidx];
        *(float4*)(smem + 20480 + row * 320 + col * 16) = ((const float4*)Wlo)[gidx];
    }
    __syncthreads();

    int w = t >> 6;
    int lane = t & 63;
    int quad = lane >> 4;
    int l16 = lane & 15;
    int m0 = blockIdx.x * 128 + w * 32;
    int ra0 = min(m0 + l16, M - 1);
    int ra1 = min(m0 + 16 + l16, M - 1);
    const float* a0p = H + (size_t)ra0 * 128 + quad * 8;
    const float* a1p = H + (size_t)ra1 * 128 + quad * 8;

    floatx4 acc[2][4];
#pragma unroll
    for (int mt = 0; mt < 2; ++mt)
#pragma unroll
        for (int nt = 0; nt < 4; ++nt) acc[mt][nt] = (floatx4){0.f, 0.f, 0.f, 0.f};

#pragma unroll
    for (int k0 = 0; k0 < 128; k0 += 32) {
        float4 af00 = *(const float4*)(a0p + k0);
        float4 af01 = *(const float4*)(a0p + k0 + 4);
        float4 af10 = *(const float4*)(a1p + k0);
        float4 af11 = *(const float4*)(a1p + k0 + 4);
        af00.x = fmaxf(af00.x, 0.f); af00.y = fmaxf(af00.y, 0.f);
        af00.z = fmaxf(af00.z, 0.f); af00.w = fmaxf(af00.w, 0.f);
        af01.x = fmaxf(af01.x, 0.f); af01.y = fmaxf(af01.y, 0.f);
        af01.z = fmaxf(af01.z, 0.f); af01.w = fmaxf(af01.w, 0.f);
        af10.x = fmaxf(af10.x, 0.f); af10.y = fmaxf(af10.y, 0.f);
        af10.z = fmaxf(af10.z, 0.f); af10.w = fmaxf(af10.w, 0.f);
        af11.x = fmaxf(af11.x, 0.f); af11.y = fmaxf(af11.y, 0.f);
        af11.z = fmaxf(af11.z, 0.f); af11.w = fmaxf(af11.w, 0.f);
        half8 bh[4], bl[4];
#pragma unroll
        for (int nt = 0; nt < 4; ++nt) {
            int off = (nt * 16 + l16) * 320 + k0 * 2 + quad * 16;
            bh[nt] = *(const half8*)(smem + off);
            bl[nt] = *(const half8*)(smem + 20480 + off);
        }
        half8 ah0, al0, ah1, al1;
        split8(af00, af01, ah0, al0);
        split8(af10, af11, ah1, al1);
#pragma unroll
        for (int nt = 0; nt < 4; ++nt) {
            acc[0][nt] = __builtin_amdgcn_mfma_f32_16x16x32_f16(ah0, bh[nt], acc[0][nt], 0, 0, 0);
            acc[1][nt] = __builtin_amdgcn_mfma_f32_16x16x32_f16(ah1, bh[nt], acc[1][nt], 0, 0, 0);
            acc[0][nt] = __builtin_amdgcn_mfma_f32_16x16x32_f16(ah0, bl[nt], acc[0][nt], 0, 0, 0);
            acc[1][nt] = __builtin_amdgcn_mfma_f32_16x16x32_f16(ah1, bl[nt], acc[1][nt], 0, 0, 0);
            acc[0][nt] = __builtin_amdgcn_mfma_f32_16x16x32_f16(al0, bh[nt], acc[0][nt], 0, 0, 0);
            acc[1][nt] = __builtin_amdgcn_mfma_f32_16x16x32_f16(al1, bh[nt], acc[1][nt], 0, 0, 0);
        }
    }

#pragma unroll
    for (int nt = 0; nt < 4; ++nt) {
        int col = nt * 16 + l16;
        float bv = bias[col];
#pragma unroll
        for (int mt = 0; mt < 2; ++mt)
#pragma unroll
            for (int r = 0; r < 4; ++r) {
                int row = m0 + mt * 16 + quad * 4 + r;
                if (row < M) out[(size_t)row * 64 + col] = acc[mt][nt][r] + bv;
            }
    }
}

// ---------------- GEMM3: relu([M,64]) @ [64,16] + bias ----------------

__global__ __launch_bounds__(256) void gemm3(const float* __restrict__ H,
                                             const float* __restrict__ W,
                                             const float* __restrict__ bias,
                                             float* __restrict__ out, int M) {
    __shared__ float Ws[64 * 16];
    __shared__ float Xs[32 * 68];
    int t = threadIdx.x;
    int m0 = blockIdx.x * 32;
    ((float4*)Ws)[t] = ((const float4*)W)[t];
#pragma unroll
    for (int i = 0; i < 2; i++) {
        int idx = t + i * 256;
        int gi = idx * 4;
        int row = gi >> 6, col = gi & 63;
        float4 v = make_float4(0.f, 0.f, 0.f, 0.f);
        if (m0 + row < M) v = *(const float4*)(H + (size_t)(m0 + row) * 64 + col);
        v.x = fmaxf(v.x, 0.f); v.y = fmaxf(v.y, 0.f);
        v.z = fmaxf(v.z, 0.f); v.w = fmaxf(v.w, 0.f);
        *(float4*)&Xs[row * 68 + col] = v;
    }
    __syncthreads();
    int node = t >> 3;
    int j = t & 7;
    float a0 = 0.f, a1 = 0.f;
#pragma unroll 8
    for (int k = 0; k < 64; ++k) {
        float xv = Xs[node * 68 + k];
        a0 += xv * Ws[k * 16 + j * 2];
        a1 += xv * Ws[k * 16 + j * 2 + 1];
    }
    int row = m0 + node;
    if (row < M) {
        a0 += bias[j * 2];
        a1 += bias[j * 2 + 1];
        float2 r = make_float2(a0, a1);
        *(float2*)(out + (size_t)row * 16 + j * 2) = r;
    }
}

// ---------------- CSR SpMM kernels (packed edges, unrolled x4) ----------------

__global__ __launch_bounds__(256) void spmm128(const int* __restrict__ rowptr,
                                               const int2* __restrict__ ssv,
                                               const float* __restrict__ T,
                                               float* __restrict__ H, int N) {
    int lane = threadIdx.x & 63;
    int node = __builtin_amdgcn_readfirstlane(blockIdx.x * 4 + (threadIdx.x >> 6));
    if (node >= N) return;
    int beg = rowptr[node], end = rowptr[node + 1];
    float a0 = 0.f, a1 = 0.f;
    int i = beg;
    int n4 = beg + ((end - beg) & ~3);
    for (; i < n4; i += 4) {
        int2 e0 = ssv[i], e1 = ssv[i + 1], e2 = ssv[i + 2], e3 = ssv[i + 3];
        const float* p0 = T + (size_t)e0.x * 128;
        const float* p1 = T + (size_t)e1.x * 128;
        const float* p2 = T + (size_t)e2.x * 128;
        const float* p3 = T + (size_t)e3.x * 128;
        float x0 = p0[lane], y0 = p0[lane + 64];
        float x1 = p1[lane], y1 = p1[lane + 64];
        float x2 = p2[lane], y2 = p2[lane + 64];
        float x3 = p3[lane], y3 = p3[lane + 64];
        float v0 = __int_as_float(e0.y), v1 = __int_as_float(e1.y);
        float v2 = __int_as_float(e2.y), v3 = __int_as_float(e3.y);
        a0 += v0 * x0; a1 += v0 * y0;
        a0 += v1 * x1; a1 += v1 * y1;
        a0 += v2 * x2; a1 += v2 * y2;
        a0 += v3 * x3; a1 += v3 * y3;
    }
    for (; i < end; ++i) {
        int2 e = ssv[i];
        float v = __int_as_float(e.y);
        const float* p = T + (size_t)e.x * 128;
        a0 += v * p[lane];
        a1 += v * p[lane + 64];
    }
    float* o = H + (size_t)node * 128;
    o[lane] = a0;
    o[lane + 64] = a1;
}

__global__ __launch_bounds__(256) void spmm64(const int* __restrict__ rowptr,
                                              const int2* __restrict__ ssv,
                                              const float* __restrict__ T,
                                              float* __restrict__ H, int N) {
    int lane = threadIdx.x & 63;
    int node = __builtin_amdgcn_readfirstlane(blockIdx.x * 4 + (threadIdx.x >> 6));
    if (node >= N) return;
    int beg = rowptr[node], end = rowptr[node + 1];
    float a = 0.f;
    int i = beg;
    int n4 = beg + ((end - beg) & ~3);
    for (; i < n4; i += 4) {
        int2 e0 = ssv[i], e1 = ssv[i + 1], e2 = ssv[i + 2], e3 = ssv[i + 3];
        float x0 = T[(size_t)e0.x * 64 + lane];
        float x1 = T[(size_t)e1.x * 64 + lane];
        float x2 = T[(size_t)e2.x * 64 + lane];
        float x3 = T[(size_t)e3.x * 64 + lane];
        a += __int_as_float(e0.y) * x0;
        a += __int_as_float(e1.y) * x1;
        a += __int_as_float(e2.y) * x2;
        a += __int_as_float(e3.y) * x3;
    }
    for (; i < end; ++i) {
        int2 e = ssv[i];
        a += __int_as_float(e.y) * T[(size_t)e.x * 64 + lane];
    }
    H[(size_t)node * 64 + lane] = a;
}

__global__ __launch_bounds__(256) void spmm_argmax(const int* __restrict__ rowptr,
                                                   const int2* __restrict__ ssv,
                                                   const float* __restrict__ T,
                                                   int* __restrict__ out, int N) {
    int lane = threadIdx.x & 63;
    int wave = threadIdx.x >> 6;
    int sub = lane >> 4;
    int fl = lane & 15;
    int node = blockIdx.x * 16 + wave * 4 + sub;
    float acc = 0.f;
    if (node < N) {
        int beg = rowptr[node], end = rowptr[node + 1];
        int i = beg;
        int n4 = beg + ((end - beg) & ~3);
        for (; i < n4; i += 4) {
            int2 e0 = ssv[i], e1 = ssv[i + 1], e2 = ssv[i + 2], e3 = ssv[i + 3];
            float x0 = T[(size_t)e0.x * 16 + fl];
            float x1 = T[(size_t)e1.x * 16 + fl];
            float x2 = T[(size_t)e2.x * 16 + fl];
            float x3 = T[(size_t)e3.x * 16 + fl];
            acc += __int_as_float(e0.y) * x0;
            acc += __int_as_float(e1.y) * x1;
            acc += __int_as_float(e2.y) * x2;
            acc += __int_as_float(e3.y) * x3;
        }
        for (; i < end; ++i) {
            int2 e = ssv[i];
            acc += __int_as_float(e.y) * T[(size_t)e.x * 16 + fl];
        }
    }
    float bv = acc;
    int bi = fl;
#pragma unroll
    for (int off = 8; off >= 1; off >>= 1) {
        float ov = __shfl_xor(bv, off, 64);
        int oi = __shfl_xor(bi, off, 64);
        if (ov > bv || (ov == bv && oi < bi)) { bv = ov; bi = oi; }
    }
    if (node < N && fl == 0) out[node] = bi;
}

// ---------------- launch ----------------

extern "C" void kernel_launch(void* const* d_in, const int* in_sizes, int n_in,
                              void* d_out, int out_size, void* d_ws, size_t ws_size,
                              hipStream_t stream) {
    const float* x  = (const float*)d_in[0];
    const int*   ei = (const int*)d_in[1];
    const float* ev = (const float*)d_in[2];
    const float* W1 = (const float*)d_in[3];
    const float* b1 = (const float*)d_in[4];
    const float* W2 = (const float*)d_in[5];
    const float* b2 = (const float*)d_in[6];
    const float* W3 = (const float*)d_in[7];
    const float* b3 = (const float*)d_in[8];
    int* out = (int*)d_out;

    int M = in_sizes[0] / 512;
    int E = in_sizes[2];
    const int* src = ei;
    const int* dst = ei + E;

    char* ws = (char*)d_ws;
    size_t off = 0;
    auto alloc = [&](size_t bytes) {
        size_t o = off;
        off += (bytes + 255) & ~(size_t)255;
        return o;
    };
    float*    tA     = (float*)(ws + alloc((size_t)M * 128 * 4));
    float*    hB     = (float*)(ws + alloc((size_t)M * 128 * 4));
    int2*     ssv    = (int2*) (ws + alloc((size_t)E * 8));
    int*      rowptr = (int*)  (ws + alloc((size_t)(M + 1) * 4));
    int*      cursor = (int*)  (ws + alloc((size_t)M * 4));
    int*      count  = (int*)  (ws + alloc((size_t)M * 4));
    int*      incl   = (int*)  (ws + alloc((size_t)M * 4));
    int*      bsum   = (int*)  (ws + alloc(4096));
    int*      boff   = (int*)  (ws + alloc(4096));
    _Float16* w1hi   = (_Float16*)(ws + alloc(512 * 128 * 2));
    _Float16* w1lo   = (_Float16*)(ws + alloc(512 * 128 * 2));
    _Float16* w2hi   = (_Float16*)(ws + alloc(128 * 64 * 2));
    _Float16* w2lo   = (_Float16*)(ws + alloc(128 * 64 * 2));

    // ---- CSR build (by dst) + weight prep ----
    hipMemsetAsync(count, 0, (size_t)M * 4, stream);
    prep_w1<<<256, 256, 0, stream>>>(W1, w1hi, w1lo);
    prep_w2<<<32, 256, 0, stream>>>(W2, w2hi, w2lo);
    hist_kernel<<<(E + 255) / 256, 256, 0, stream>>>(dst, count, E);
    int NB = (M + 1023) / 1024;
    scan_a<<<NB, 1024, 0, stream>>>(count, incl, bsum, M);
    scan_b<<<1, 1024, 0, stream>>>(bsum, boff, NB);
    scan_c<<<NB, 1024, 0, stream>>>(count, incl, boff, rowptr, cursor, M);
    scatter_kernel<<<(E + 255) / 256, 256, 0, stream>>>(src, dst, ev, cursor, ssv, E);

    // ---- layer 1 ----
    gemm1_mfma<<<(M + 127) / 128, 256, 0, stream>>>(x, w1hi, w1lo, b1, tA, M);
    spmm128<<<(M + 3) / 4, 256, 0, stream>>>(rowptr, ssv, tA, hB, M);
    // ---- layer 2 (relu fused into gemm2 input) ----
    gemm2_mfma<<<(M + 127) / 128, 256, 0, stream>>>(hB, w2hi, w2lo, b2, tA, M);
    spmm64<<<(M + 3) / 4, 256, 0, stream>>>(rowptr, ssv, tA, hB, M);
    // ---- layer 3 + argmax ----
    gemm3<<<(M + 31) / 32, 256, 0, stream>>>(hB, W3, b3, tA, M);
    spmm_argmax<<<(M + 15) / 16, 256, 0, stream>>>(rowptr, ssv, tA, out, M);
}

// Round 5
// 694.362 us; speedup vs baseline: 1.0878x; 1.0878x over previous
//
#include <hip/hip_runtime.h>

typedef _Float16 half8 __attribute__((ext_vector_type(8)));
typedef float floatx4 __attribute__((ext_vector_type(4)));

#define BSHIFT 7              // 128 nodes per bucket
#define BMASK 127
#define EPB 8192              // edges per pass-1 block
#define P2CAP 4096            // LDS edge stash per bucket (mean ~2046, 45 sigma)

// global -> LDS async copy, 16B per lane.
__device__ __forceinline__ void g2lds16(const void* g, void* l) {
    __builtin_amdgcn_global_load_lds(
        (const __attribute__((address_space(1))) void*)(unsigned long long)g,
        (__attribute__((address_space(3))) void*)(unsigned int)(unsigned long long)l,
        16, 0, 0);
}

// ---------------- CSR build: two-level counting sort, LDS atomics only ----------------

// p1a: per-block histogram of dst buckets
__global__ __launch_bounds__(256) void p1a_hist(const int* __restrict__ dst,
                                                int* __restrict__ hist,
                                                int E, int NBUCK) {
    extern __shared__ int lh[];
    int b = blockIdx.x, t = threadIdx.x;
    for (int k = t; k < NBUCK; k += 256) lh[k] = 0;
    __syncthreads();
    int e0 = b * EPB;
    int eend = min(e0 + EPB, E);
    for (int i = e0 + t; i < eend; i += 256)
        atomicAdd(&lh[dst[i] >> BSHIFT], 1);
    __syncthreads();
    for (int k = t; k < NBUCK; k += 256) hist[(size_t)b * NBUCK + k] = lh[k];
}

// p1b: per-bucket exclusive scan over blocks (thread k loops blocks; coalesced)
__global__ __launch_bounds__(256) void p1b_scan(const int* __restrict__ hist,
                                                int* __restrict__ blockOff,
                                                int* __restrict__ btot,
                                                int NBLK, int NBUCK) {
    int k = blockIdx.x * 256 + threadIdx.x;
    if (k < NBUCK) {
        int run = 0;
        for (int b = 0; b < NBLK; ++b) {
            int c = hist[(size_t)b * NBUCK + k];
            blockOff[(size_t)b * NBUCK + k] = run;
            run += c;
        }
        btot[k] = run;
    }
}

// p1c: exclusive scan of bucket totals (NBUCK <= 1024; M <= 131071)
__global__ __launch_bounds__(1024) void p1c_bscan(const int* __restrict__ btot,
                                                  int* __restrict__ bstart,
                                                  int* __restrict__ rowptr,
                                                  int NBUCK, int M, int E) {
    __shared__ int s[1024];
    int tid = threadIdx.x;
    int v = (tid < NBUCK) ? btot[tid] : 0;
    s[tid] = v;
    __syncthreads();
    for (int off = 1; off < 1024; off <<= 1) {
        int t = (tid >= off) ? s[tid - off] : 0;
        __syncthreads();
        s[tid] += t;
        __syncthreads();
    }
    if (tid < NBUCK) bstart[tid] = s[tid] - v;
    if (tid == 0) rowptr[M] = E;
}

// p1d: bucket scatter. LDS cursors -> consecutive output runs per (block,bucket).
__global__ __launch_bounds__(256) void p1d_scatter(const int* __restrict__ src,
                                                   const int* __restrict__ dst,
                                                   const float* __restrict__ val,
                                                   const int* __restrict__ bstart,
                                                   const int* __restrict__ blockOff,
                                                   int2* __restrict__ tmp,
                                                   int E, int NBUCK) {
    extern __shared__ int cur[];
    int b = blockIdx.x, t = threadIdx.x;
    for (int k = t; k < NBUCK; k += 256)
        cur[k] = bstart[k] + blockOff[(size_t)b * NBUCK + k];
    __syncthreads();
    int e0 = b * EPB;
    int eend = min(e0 + EPB, E);
    for (int i = e0 + t; i < eend; i += 256) {
        int d = dst[i];
        int p = atomicAdd(&cur[d >> BSHIFT], 1);
        int2 pk;
        pk.x = src[i] | ((d & BMASK) << 20);   // src < 2^20
        pk.y = __float_as_int(val[i]);
        tmp[p] = pk;
    }
}

// p2: per-bucket final sort (block-local; all writes single-XCD, L2-resident)
__global__ __launch_bounds__(256) void p2_sort(const int2* __restrict__ tmp,
                                               const int* __restrict__ bstart,
                                               const int* __restrict__ btot,
                                               int* __restrict__ rowptr,
                                               int2* __restrict__ ssv, int M) {
    __shared__ int2 ebuf[P2CAP];
    __shared__ int h[128], sc[128], curs[128];
    int k = blockIdx.x, t = threadIdx.x;
    int base = bstart[k], n = btot[k];
    for (int j = t; j < 128; j += 256) h[j] = 0;
    __syncthreads();
    int nl = min(n, P2CAP);
    for (int i = t; i < nl; i += 256) {
        int2 e = tmp[base + i];
        ebuf[i] = e;
        atomicAdd(&h[e.x >> 20], 1);
    }
    for (int i = P2CAP + t; i < n; i += 256) {   // overflow: never in practice
        int2 e = tmp[base + i];
        atomicAdd(&h[e.x >> 20], 1);
    }
    __syncthreads();
    if (t < 128) sc[t] = h[t];
    __syncthreads();
    for (int off = 1; off < 128; off <<= 1) {
        int v = (t < 128 && t >= off) ? sc[t - off] : 0;
        __syncthreads();
        if (t < 128) sc[t] += v;
        __syncthreads();
    }
    if (t < 128) {
        int node = (k << BSHIFT) + t;
        int excl = sc[t] - h[t];
        if (node < M) rowptr[node] = base + excl;
        curs[t] = excl;
    }
    __syncthreads();
    for (int i = t; i < nl; i += 256) {
        int2 e = ebuf[i];
        int p = atomicAdd(&curs[e.x >> 20], 1);
        int2 o; o.x = e.x & 0xFFFFF; o.y = e.y;
        ssv[base + p] = o;
    }
    for (int i = P2CAP + t; i < n; i += 256) {
        int2 e = tmp[base + i];
        int p = atomicAdd(&curs[e.x >> 20], 1);
        int2 o; o.x = e.x & 0xFFFFF; o.y = e.y;
        ssv[base + p] = o;
    }
}

// ---------------- weight prep: fp32 -> fp16 hi/lo, transposed [n][k] ----------------

__global__ __launch_bounds__(256) void prep_w1(const float* __restrict__ W1,
                                               _Float16* __restrict__ Whi,
                                               _Float16* __restrict__ Wlo) {
    int tid = blockIdx.x * 256 + threadIdx.x;   // 65536
    int n = tid >> 9;
    int k = tid & 511;
    float w = W1[(size_t)k * 128 + n];
    _Float16 h = (_Float16)w;
    Whi[tid] = h;
    Wlo[tid] = (_Float16)(w - (float)h);
}

__global__ __launch_bounds__(256) void prep_w2(const float* __restrict__ W2,
                                               _Float16* __restrict__ Whi,
                                               _Float16* __restrict__ Wlo) {
    int tid = blockIdx.x * 256 + threadIdx.x;   // 8192
    int n = tid >> 7;
    int k = tid & 127;
    float w = W2[(size_t)k * 64 + n];
    _Float16 h = (_Float16)w;
    Whi[tid] = h;
    Wlo[tid] = (_Float16)(w - (float)h);
}

__device__ __forceinline__ void split8(float4 f0, float4 f1, half8& h, half8& l) {
    float f[8] = {f0.x, f0.y, f0.z, f0.w, f1.x, f1.y, f1.z, f1.w};
#pragma unroll
    for (int j = 0; j < 8; ++j) {
        _Float16 hi = (_Float16)f[j];
        h[j] = hi;
        l[j] = (_Float16)(f[j] - (float)hi);
    }
}

// ---------------- GEMM1: [M,512]@[512,128]+b1, split-fp16 MFMA ----------------

__global__ __launch_bounds__(256) void gemm1_mfma(const float* __restrict__ X,
                                                  const _Float16* __restrict__ Whi,
                                                  const _Float16* __restrict__ Wlo,
                                                  const float* __restrict__ bias,
                                                  float* __restrict__ out, int M) {
    __shared__ char smem[2 * 16384];
    int t = threadIdx.x;
    int w = t >> 6;
    int lane = t & 63;
    int quad = lane >> 4;
    int l16 = lane & 15;
    int bm = blockIdx.x * 128;
    int m0 = bm + w * 32;

    int ra0 = min(m0 + l16, M - 1);
    int ra1 = min(m0 + 16 + l16, M - 1);
    const float* a0p = X + (size_t)ra0 * 512 + quad * 8;
    const float* a1p = X + (size_t)ra1 * 512 + quad * 8;

    int chunk0 = w * 4;
    const _Float16* gsrc[4];
#pragma unroll
    for (int c = 0; c < 4; ++c) {
        int idx = (chunk0 + c) * 1024 + lane * 16;
        int sec = idx >> 13;
        int row = (idx & 8191) >> 6;
        int kch = (idx >> 4) & 3;
        gsrc[c] = (sec ? Wlo : Whi) + (size_t)row * 512 + kch * 8;
    }
#pragma unroll
    for (int c = 0; c < 4; ++c)
        g2lds16(gsrc[c], smem + (chunk0 + c) * 1024);
    float4 af00 = *(const float4*)(a0p);
    float4 af01 = *(const float4*)(a0p + 4);
    float4 af10 = *(const float4*)(a1p);
    float4 af11 = *(const float4*)(a1p + 4);

    floatx4 acc[2][8];
#pragma unroll
    for (int mt = 0; mt < 2; ++mt)
#pragma unroll
        for (int nt = 0; nt < 8; ++nt) acc[mt][nt] = (floatx4){0.f, 0.f, 0.f, 0.f};

    for (int i = 0; i < 16; ++i) {
        int k0 = i * 32;
        __syncthreads();
        if (i < 15) {
            char* nbuf = smem + ((i + 1) & 1) * 16384;
#pragma unroll
            for (int c = 0; c < 4; ++c)
                g2lds16(gsrc[c] + k0 + 32, nbuf + (chunk0 + c) * 1024);
        }
        float4 nf00 = af00, nf01 = af01, nf10 = af10, nf11 = af11;
        if (i < 15) {
            nf00 = *(const float4*)(a0p + k0 + 32);
            nf01 = *(const float4*)(a0p + k0 + 36);
            nf10 = *(const float4*)(a1p + k0 + 32);
            nf11 = *(const float4*)(a1p + k0 + 36);
        }
        const char* buf = smem + (i & 1) * 16384;
        half8 bh[8], bl[8];
#pragma unroll
        for (int nt = 0; nt < 8; ++nt) {
            int off = (nt * 16 + l16) * 64 + quad * 16;
            bh[nt] = *(const half8*)(buf + off);
            bl[nt] = *(const half8*)(buf + 8192 + off);
        }
        half8 ah0, al0, ah1, al1;
        split8(af00, af01, ah0, al0);
        split8(af10, af11, ah1, al1);
#pragma unroll
        for (int nt = 0; nt < 8; ++nt) {
            acc[0][nt] = __builtin_amdgcn_mfma_f32_16x16x32_f16(ah0, bh[nt], acc[0][nt], 0, 0, 0);
            acc[1][nt] = __builtin_amdgcn_mfma_f32_16x16x32_f16(ah1, bh[nt], acc[1][nt], 0, 0, 0);
            acc[0][nt] = __builtin_amdgcn_mfma_f32_16x16x32_f16(ah0, bl[nt], acc[0][nt], 0, 0, 0);
            acc[1][nt] = __builtin_amdgcn_mfma_f32_16x16x32_f16(ah1, bl[nt], acc[1][nt], 0, 0, 0);
            acc[0][nt] = __builtin_amdgcn_mfma_f32_16x16x32_f16(al0, bh[nt], acc[0][nt], 0, 0, 0);
            acc[1][nt] = __builtin_amdgcn_mfma_f32_16x16x32_f16(al1, bh[nt], acc[1][nt], 0, 0, 0);
        }
        af00 = nf00; af01 = nf01; af10 = nf10; af11 = nf11;
    }

#pragma unroll
    for (int nt = 0; nt < 8; ++nt) {
        int col = nt * 16 + l16;
        float bv = bias[col];
#pragma unroll
        for (int mt = 0; mt < 2; ++mt)
#pragma unroll
            for (int r = 0; r < 4; ++r) {
                int row = m0 + mt * 16 + quad * 4 + r;
                if (row < M) out[(size_t)row * 128 + col] = acc[mt][nt][r] + bv;
            }
    }
}

// ---------------- GEMM2: relu([M,128])@[128,64]+b2, split-fp16 MFMA ----------------

__global__ __launch_bounds__(256) void gemm2_mfma(const float* __restrict__ H,
                                                  const _Float16* __restrict__ Whi,
                                                  const _Float16* __restrict__ Wlo,
                                                  const float* __restrict__ bias,
                                                  float* __restrict__ out, int M) {
    __shared__ char smem[2 * 64 * 320];
    int t = threadIdx.x;
#pragma unroll
    for (int i = 0; i < 4; ++i) {
        int gidx = i * 256 + t;
        int row = gidx >> 4, col = gidx & 15;
        *(float4*)(smem + row * 320 + col * 16) = ((const float4*)Whi)[gidx];
        *(float4*)(smem + 20480 + row * 320 + col * 16) = ((const float4*)Wlo)[gidx];
    }
    __syncthreads();

    int w = t >> 6;
    int lane = t & 63;
    int quad = lane >> 4;
    int l16 = lane & 15;
    int m0 = blockIdx.x * 128 + w * 32;
    int ra0 = min(m0 + l16, M - 1);
    int ra1 = min(m0 + 16 + l16, M - 1);
    const float* a0p = H + (size_t)ra0 * 128 + quad * 8;
    const float* a1p = H + (size_t)ra1 * 128 + quad * 8;

    floatx4 acc[2][4];
#pragma unroll
    for (int mt = 0; mt < 2; ++mt)
#pragma unroll
        for (int nt = 0; nt < 4; ++nt) acc[mt][nt] = (floatx4){0.f, 0.f, 0.f, 0.f};

#pragma unroll
    for (int k0 = 0; k0 < 128; k0 += 32) {
        float4 af00 = *(const float4*)(a0p + k0);
        float4 af01 = *(const float4*)(a0p + k0 + 4);
        float4 af10 = *(const float4*)(a1p + k0);
        float4 af11 = *(const float4*)(a1p + k0 + 4);
        af00.x = fmaxf(af00.x, 0.f); af00.y = fmaxf(af00.y, 0.f);
        af00.z = fmaxf(af00.z, 0.f); af00.w = fmaxf(af00.w, 0.f);
        af01.x = fmaxf(af01.x, 0.f); af01.y = fmaxf(af01.y, 0.f);
        af01.z = fmaxf(af01.z, 0.f); af01.w = fmaxf(af01.w, 0.f);
        af10.x = fmaxf(af10.x, 0.f); af10.y = fmaxf(af10.y, 0.f);
        af10.z = fmaxf(af10.z, 0.f); af10.w = fmaxf(af10.w, 0.f);
        af11.x = fmaxf(af11.x, 0.f); af11.y = fmaxf(af11.y, 0.f);
        af11.z = fmaxf(af11.z, 0.f); af11.w = fmaxf(af11.w, 0.f);
        half8 bh[4], bl[4];
#pragma unroll
        for (int nt = 0; nt < 4; ++nt) {
            int off = (nt * 16 + l16) * 320 + k0 * 2 + quad * 16;
            bh[nt] = *(const half8*)(smem + off);
            bl[nt] = *(const half8*)(smem + 20480 + off);
        }
        half8 ah0, al0, ah1, al1;
        split8(af00, af01, ah0, al0);
        split8(af10, af11, ah1, al1);
#pragma unroll
        for (int nt = 0; nt < 4; ++nt) {
            acc[0][nt] = __builtin_amdgcn_mfma_f32_16x16x32_f16(ah0, bh[nt], acc[0][nt], 0, 0, 0);
            acc[1][nt] = __builtin_amdgcn_mfma_f32_16x16x32_f16(ah1, bh[nt], acc[1][nt], 0, 0, 0);
            acc[0][nt] = __builtin_amdgcn_mfma_f32_16x16x32_f16(ah0, bl[nt], acc[0][nt], 0, 0, 0);
            acc[1][nt] = __builtin_amdgcn_mfma_f32_16x16x32_f16(ah1, bl[nt], acc[1][nt], 0, 0, 0);
            acc[0][nt] = __builtin_amdgcn_mfma_f32_16x16x32_f16(al0, bh[nt], acc[0][nt], 0, 0, 0);
            acc[1][nt] = __builtin_amdgcn_mfma_f32_16x16x32_f16(al1, bh[nt], acc[1][nt], 0, 0, 0);
        }
    }

#pragma unroll
    for (int nt = 0; nt < 4; ++nt) {
        int col = nt * 16 + l16;
        float bv = bias[col];
#pragma unroll
        for (int mt = 0; mt < 2; ++mt)
#pragma unroll
            for (int r = 0; r < 4; ++r) {
                int row = m0 + mt * 16 + quad * 4 + r;
                if (row < M) out[(size_t)row * 64 + col] = acc[mt][nt][r] + bv;
            }
    }
}

// ---------------- GEMM3: relu([M,64]) @ [64,16] + bias ----------------

__global__ __launch_bounds__(256) void gemm3(const float* __restrict__ H,
                                             const float* __restrict__ W,
                                             const float* __restrict__ bias,
                                             float* __restrict__ out, int M) {
    __shared__ float Ws[64 * 16];
    __shared__ float Xs[32 * 68];
    int t = threadIdx.x;
    int m0 = blockIdx.x * 32;
    ((float4*)Ws)[t] = ((const float4*)W)[t];
#pragma unroll
    for (int i = 0; i < 2; i++) {
        int idx = t + i * 256;
        int gi = idx * 4;
        int row = gi >> 6, col = gi & 63;
        float4 v = make_float4(0.f, 0.f, 0.f, 0.f);
        if (m0 + row < M) v = *(const float4*)(H + (size_t)(m0 + row) * 64 + col);
        v.x = fmaxf(v.x, 0.f); v.y = fmaxf(v.y, 0.f);
        v.z = fmaxf(v.z, 0.f); v.w = fmaxf(v.w, 0.f);
        *(float4*)&Xs[row * 68 + col] = v;
    }
    __syncthreads();
    int node = t >> 3;
    int j = t & 7;
    float a0 = 0.f, a1 = 0.f;
#pragma unroll 8
    for (int k = 0; k < 64; ++k) {
        float xv = Xs[node * 68 + k];
        a0 += xv * Ws[k * 16 + j * 2];
        a1 += xv * Ws[k * 16 + j * 2 + 1];
    }
    int row = m0 + node;
    if (row < M) {
        a0 += bias[j * 2];
        a1 += bias[j * 2 + 1];
        float2 r = make_float2(a0, a1);
        *(float2*)(out + (size_t)row * 16 + j * 2) = r;
    }
}

// ---------------- CSR SpMM kernels (packed edges, unrolled x4) ----------------

__global__ __launch_bounds__(256) void spmm128(const int* __restrict__ rowptr,
                                               const int2* __restrict__ ssv,
                                               const float* __restrict__ T,
                                               float* __restrict__ H, int N) {
    int lane = threadIdx.x & 63;
    int node = __builtin_amdgcn_readfirstlane(blockIdx.x * 4 + (threadIdx.x >> 6));
    if (node >= N) return;
    int beg = rowptr[node], end = rowptr[node + 1];
    float a0 = 0.f, a1 = 0.f;
    int i = beg;
    int n4 = beg + ((end - beg) & ~3);
    for (; i < n4; i += 4) {
        int2 e0 = ssv[i], e1 = ssv[i + 1], e2 = ssv[i + 2], e3 = ssv[i + 3];
        const float* p0 = T + (size_t)e0.x * 128;
        const float* p1 = T + (size_t)e1.x * 128;
        const float* p2 = T + (size_t)e2.x * 128;
        const float* p3 = T + (size_t)e3.x * 128;
        float x0 = p0[lane], y0 = p0[lane + 64];
        float x1 = p1[lane], y1 = p1[lane + 64];
        float x2 = p2[lane], y2 = p2[lane + 64];
        float x3 = p3[lane], y3 = p3[lane + 64];
        float v0 = __int_as_float(e0.y), v1 = __int_as_float(e1.y);
        float v2 = __int_as_float(e2.y), v3 = __int_as_float(e3.y);
        a0 += v0 * x0; a1 += v0 * y0;
        a0 += v1 * x1; a1 += v1 * y1;
        a0 += v2 * x2; a1 += v2 * y2;
        a0 += v3 * x3; a1 += v3 * y3;
    }
    for (; i < end; ++i) {
        int2 e = ssv[i];
        float v = __int_as_float(e.y);
        const float* p = T + (size_t)e.x * 128;
        a0 += v * p[lane];
        a1 += v * p[lane + 64];
    }
    float* o = H + (size_t)node * 128;
    o[lane] = a0;
    o[lane + 64] = a1;
}

__global__ __launch_bounds__(256) void spmm64(const int* __restrict__ rowptr,
                                              const int2* __restrict__ ssv,
                                              const float* __restrict__ T,
                                              float* __restrict__ H, int N) {
    int lane = threadIdx.x & 63;
    int node = __builtin_amdgcn_readfirstlane(blockIdx.x * 4 + (threadIdx.x >> 6));
    if (node >= N) return;
    int beg = rowptr[node], end = rowptr[node + 1];
    float a = 0.f;
    int i = beg;
    int n4 = beg + ((end - beg) & ~3);
    for (; i < n4; i += 4) {
        int2 e0 = ssv[i], e1 = ssv[i + 1], e2 = ssv[i + 2], e3 = ssv[i + 3];
        float x0 = T[(size_t)e0.x * 64 + lane];
        float x1 = T[(size_t)e1.x * 64 + lane];
        float x2 = T[(size_t)e2.x * 64 + lane];
        float x3 = T[(size_t)e3.x * 64 + lane];
        a += __int_as_float(e0.y) * x0;
        a += __int_as_float(e1.y) * x1;
        a += __int_as_float(e2.y) * x2;
        a += __int_as_float(e3.y) * x3;
    }
    for (; i < end; ++i) {
        int2 e = ssv[i];
        a += __int_as_float(e.y) * T[(size_t)e.x * 64 + lane];
    }
    H[(size_t)node * 64 + lane] = a;
}

__global__ __launch_bounds__(256) void spmm_argmax(const int* __restrict__ rowptr,
                                                   const int2* __restrict__ ssv,
                                                   const float* __restrict__ T,
                                                   int* __restrict__ out, int N) {
    int lane = threadIdx.x & 63;
    int wave = threadIdx.x >> 6;
    int sub = lane >> 4;
    int fl = lane & 15;
    int node = blockIdx.x * 16 + wave * 4 + sub;
    float acc = 0.f;
    if (node < N) {
        int beg = rowptr[node], end = rowptr[node + 1];
        int i = beg;
        int n4 = beg + ((end - beg) & ~3);
        for (; i < n4; i += 4) {
            int2 e0 = ssv[i], e1 = ssv[i + 1], e2 = ssv[i + 2], e3 = ssv[i + 3];
            float x0 = T[(size_t)e0.x * 16 + fl];
            float x1 = T[(size_t)e1.x * 16 + fl];
            float x2 = T[(size_t)e2.x * 16 + fl];
            float x3 = T[(size_t)e3.x * 16 + fl];
            acc += __int_as_float(e0.y) * x0;
            acc += __int_as_float(e1.y) * x1;
            acc += __int_as_float(e2.y) * x2;
            acc += __int_as_float(e3.y) * x3;
        }
        for (; i < end; ++i) {
            int2 e = ssv[i];
            acc += __int_as_float(e.y) * T[(size_t)e.x * 16 + fl];
        }
    }
    float bv = acc;
    int bi = fl;
#pragma unroll
    for (int off = 8; off >= 1; off >>= 1) {
        float ov = __shfl_xor(bv, off, 64);
        int oi = __shfl_xor(bi, off, 64);
        if (ov > bv || (ov == bv && oi < bi)) { bv = ov; bi = oi; }
    }
    if (node < N && fl == 0) out[node] = bi;
}

// ---------------- launch ----------------

extern "C" void kernel_launch(void* const* d_in, const int* in_sizes, int n_in,
                              void* d_out, int out_size, void* d_ws, size_t ws_size,
                              hipStream_t stream) {
    const float* x  = (const float*)d_in[0];
    const int*   ei = (const int*)d_in[1];
    const float* ev = (const float*)d_in[2];
    const float* W1 = (const float*)d_in[3];
    const float* b1 = (const float*)d_in[4];
    const float* W2 = (const float*)d_in[5];
    const float* b2 = (const float*)d_in[6];
    const float* W3 = (const float*)d_in[7];
    const float* b3 = (const float*)d_in[8];
    int* out = (int*)d_out;

    int M = in_sizes[0] / 512;
    int E = in_sizes[2];
    const int* src = ei;
    const int* dst = ei + E;

    int NBUCK = (M + BMASK) >> BSHIFT;        // 782 for M=100k (<=1024 required)
    int NBLK  = (E + EPB - 1) / EPB;          // 196 for E=1.6M

    char* ws = (char*)d_ws;
    size_t off = 0;
    auto alloc = [&](size_t bytes) {
        size_t o = off;
        off += (bytes + 255) & ~(size_t)255;
        return o;
    };
    float*    tA      = (float*)(ws + alloc((size_t)M * 128 * 4));
    float*    hB      = (float*)(ws + alloc((size_t)M * 128 * 4));
    int2*     ssv     = (int2*) (ws + alloc((size_t)E * 8));
    int*      rowptr  = (int*)  (ws + alloc((size_t)(M + 1) * 4));
    int*      hist    = (int*)  (ws + alloc((size_t)NBLK * NBUCK * 4));
    int*      blockOff= (int*)  (ws + alloc((size_t)NBLK * NBUCK * 4));
    int*      btot    = (int*)  (ws + alloc((size_t)NBUCK * 4));
    int*      bstart  = (int*)  (ws + alloc((size_t)NBUCK * 4));
    _Float16* w1hi    = (_Float16*)(ws + alloc(512 * 128 * 2));
    _Float16* w1lo    = (_Float16*)(ws + alloc(512 * 128 * 2));
    _Float16* w2hi    = (_Float16*)(ws + alloc(128 * 64 * 2));
    _Float16* w2lo    = (_Float16*)(ws + alloc(128 * 64 * 2));
    int2*     tmp     = (int2*)hB;   // pass-1 staging overlays hB (free before SpMM)

    // ---- weight prep + CSR build (LDS-atomic counting sort) ----
    prep_w1<<<256, 256, 0, stream>>>(W1, w1hi, w1lo);
    prep_w2<<<32, 256, 0, stream>>>(W2, w2hi, w2lo);
    p1a_hist<<<NBLK, 256, NBUCK * 4, stream>>>(dst, hist, E, NBUCK);
    p1b_scan<<<(NBUCK + 255) / 256, 256, 0, stream>>>(hist, blockOff, btot, NBLK, NBUCK);
    p1c_bscan<<<1, 1024, 0, stream>>>(btot, bstart, rowptr, NBUCK, M, E);
    p1d_scatter<<<NBLK, 256, NBUCK * 4, stream>>>(src, dst, ev, bstart, blockOff, tmp, E, NBUCK);
    p2_sort<<<NBUCK, 256, 0, stream>>>(tmp, bstart, btot, rowptr, ssv, M);

    // ---- layer 1 ----
    gemm1_mfma<<<(M + 127) / 128, 256, 0, stream>>>(x, w1hi, w1lo, b1, tA, M);
    spmm128<<<(M + 3) / 4, 256, 0, stream>>>(rowptr, ssv, tA, hB, M);
    // ---- layer 2 (relu fused into gemm2 input) ----
    gemm2_mfma<<<(M + 127) / 128, 256, 0, stream>>>(hB, w2hi, w2lo, b2, tA, M);
    spmm64<<<(M + 3) / 4, 256, 0, stream>>>(rowptr, ssv, tA, hB, M);
    // ---- layer 3 + argmax ----
    gemm3<<<(M + 31) / 32, 256, 0, stream>>>(hB, W3, b3, tA, M);
    spmm_argmax<<<(M + 15) / 16, 256, 0, stream>>>(rowptr, ssv, tA, out, M);
}